// Round 12
// baseline (172.304 us; speedup 1.0000x reference)
//
#include <hip/hip_runtime.h>

static constexpr int NND = 100000;        // nodes
static constexpr int NED = 3200000;       // edges (before self-loops)
static constexpr int NB  = (NND + 255) / 256;   // 391 buckets of 256 nodes
static constexpr int NCHUNK = 256;              // edge chunks
static constexpr int EPC = NED / NCHUNK;        // 12500 edges per chunk (=3125*4)
static constexpr int SCAN_N = NB * NCHUNK;      // 100096
static constexpr int NSB = (SCAN_N + 1023) / 1024;  // 98 scan blocks

typedef int int4n __attribute__((ext_vector_type(4)));        // native vec for nontemporal builtins
typedef _Float16 half4n __attribute__((ext_vector_type(4)));  // 8 B fp16 quad
typedef _Float16 half8n __attribute__((ext_vector_type(8)));  // 16 B fp16 oct

// ---------------- partition pass 1: per-(chunk,bucket) histogram ----------------

__global__ void k_hist(const int* __restrict__ dst, int* __restrict__ counts) {
    __shared__ int h[NB];
    for (int i = threadIdx.x; i < NB; i += 256) h[i] = 0;
    __syncthreads();
    int c = blockIdx.x;
    const int4n* d4 = reinterpret_cast<const int4n*>(dst + c * EPC);
    for (int i = threadIdx.x; i < EPC / 4; i += 256) {
        int4n v = d4[i];
        atomicAdd(&h[v.x >> 8], 1);
        atomicAdd(&h[v.y >> 8], 1);
        atomicAdd(&h[v.z >> 8], 1);
        atomicAdd(&h[v.w >> 8], 1);
    }
    __syncthreads();
    for (int b = threadIdx.x; b < NB; b += 256)
        counts[b * NCHUNK + c] = h[b];   // bucket-major for the scan
}

// ---------------- scan (exclusive within 1024-chunk) + raw block sums ----------------

__global__ void k_scan1(const int* __restrict__ in, int* __restrict__ excl,
                        int* __restrict__ blockSums, int n) {
    __shared__ int lds[256];
    int tid = threadIdx.x;
    int base = blockIdx.x * 1024 + tid * 4;
    int v[4]; int sum = 0;
#pragma unroll
    for (int k = 0; k < 4; ++k) { int idx = base + k; v[k] = (idx < n) ? in[idx] : 0; sum += v[k]; }
    lds[tid] = sum; __syncthreads();
    for (int off = 1; off < 256; off <<= 1) {
        int x = lds[tid];
        int y = (tid >= off) ? lds[tid - off] : 0;
        __syncthreads();
        lds[tid] = x + y;
        __syncthreads();
    }
    int run = lds[tid] - sum;
#pragma unroll
    for (int k = 0; k < 4; ++k) { int idx = base + k; if (idx < n) excl[idx] = run; run += v[k]; }
    if (tid == 0) blockSums[blockIdx.x] = lds[255];
}

// in-block exclusive scan of the 98 raw block sums (redundant per block, replaces k_scan2)
__device__ __forceinline__ void scan_bsums(const int* __restrict__ bsums, int* sbs, int t) {
    int orig = 0;
    if (t < 128) { orig = (t < NSB) ? bsums[t] : 0; sbs[t] = orig; }
    __syncthreads();
    for (int off = 1; off < 128; off <<= 1) {
        int v = 0;
        if (t < 128) { v = sbs[t]; if (t >= off) v += sbs[t - off]; }
        __syncthreads();
        if (t < 128) sbs[t] = v;
        __syncthreads();
    }
    if (t < 128) sbs[t] -= orig;   // exclusive
    __syncthreads();
}

// ---------------- partition pass 2: scatter into bucket runs ----------------
// pack = src | (dst&255)<<20   (src < 2^20)

__global__ void k_part(const int* __restrict__ src, const int* __restrict__ dst,
                       const int* __restrict__ excl, const int* __restrict__ bsums,
                       int* __restrict__ tmp) {
    __shared__ int cur[NB];
    __shared__ int sbs[128];
    int c = blockIdx.x, t = threadIdx.x;
    scan_bsums(bsums, sbs, t);
    for (int b = t; b < NB; b += 256) {
        int i = b * NCHUNK + c;
        cur[b] = excl[i] + sbs[i >> 10];
    }
    __syncthreads();
    const int4n* s4 = reinterpret_cast<const int4n*>(src + c * EPC);
    const int4n* d4 = reinterpret_cast<const int4n*>(dst + c * EPC);
    for (int i = t; i < EPC / 4; i += 256) {
        int4n sv = __builtin_nontemporal_load(&s4[i]);   // src/dst: genuinely last-read here
        int4n dv = __builtin_nontemporal_load(&d4[i]);
        int ss[4] = {sv.x, sv.y, sv.z, sv.w};
        int dd[4] = {dv.x, dv.y, dv.z, dv.w};
#pragma unroll
        for (int k = 0; k < 4; ++k) {
            int b = dd[k] >> 8;
            int pos = atomicAdd(&cur[b], 1);
            tmp[pos] = ss[k] | ((dd[k] & 255) << 20);    // PLAIN store: L2 write-combines runs
        }
    }
}

// ------- per-bucket: deg/dinv/rowptr + CSR fill + fused layer-1 prep -------

__global__ void k_bucket(const int* __restrict__ excl, const int* __restrict__ bsums,
                         const int* __restrict__ tmp,
                         int* __restrict__ ssrc, int* __restrict__ rowptr,
                         float* __restrict__ dinv, const float* __restrict__ x,
                         half4n* __restrict__ t4) {
    __shared__ int cnt[256];
    __shared__ int lds[256];
    __shared__ int sbs[128];
    int b = blockIdx.x, t = threadIdx.x;
    scan_bsums(bsums, sbs, t);
    int i0 = b * NCHUNK;
    int start = excl[i0] + sbs[i0 >> 10];
    int end;
    if (b == NB - 1) end = NED;
    else { int i1 = (b + 1) * NCHUNK; end = excl[i1] + sbs[i1 >> 10]; }
    cnt[t] = 0;
    __syncthreads();
    for (int i = start + t; i < end; i += 256)
        atomicAdd(&cnt[tmp[i] >> 20], 1);
    __syncthreads();
    int v = cnt[t];
    lds[t] = v; __syncthreads();
    for (int off = 1; off < 256; off <<= 1) {
        int xv = lds[t];
        int y = (t >= off) ? lds[t - off] : 0;
        __syncthreads();
        lds[t] = xv + y;
        __syncthreads();
    }
    int node = b * 256 + t;
    int rp = start + lds[t] - v;
    if (node < NND) {
        rowptr[node] = rp;
        float d = rsqrtf((float)(v + 1));  // +1 self-loop
        dinv[node] = d;
        const float* xr = x + (size_t)node * 3;   // fused layer-1 prep (fp16 table)
        half4n o;
        o.x = (_Float16)(xr[0] * d); o.y = (_Float16)(xr[1] * d);
        o.z = (_Float16)(xr[2] * d); o.w = (_Float16)0.f;
        t4[node] = o;
    }
    if (b == 0 && t == 0) rowptr[NND] = NED;
    cnt[t] = rp;
    __syncthreads();
    for (int i = start + t; i < end; i += 256) {
        int p = tmp[i];
        int pos = atomicAdd(&cnt[p >> 20], 1);
        ssrc[pos] = p & 0xFFFFF;
    }
}

// ------- layer1: gather fp16 4-wide + fused 3->16 matmul, fp16 table out -------
// ssrc is nt-loaded (stream-once) so the t4 table stays L2-resident.

__global__ void k_g4mm1(const int* __restrict__ rowptr, const int* __restrict__ ssrc,
                        const half4n* __restrict__ t4, const float* __restrict__ dinv,
                        const float* __restrict__ W1, const float* __restrict__ b1,
                        _Float16* __restrict__ t16, int n) {
    __shared__ float sW[48];
    __shared__ float sb[16];
    if (threadIdx.x < 48) sW[threadIdx.x] = W1[threadIdx.x];
    if (threadIdx.x < 16) sb[threadIdx.x] = b1[threadIdx.x];
    __syncthreads();
    int node = blockIdx.x * blockDim.x + threadIdx.x;
    if (node >= n) return;

    float a0, a1, a2;
    {
        half4n a = t4[node];
        a0 = (float)a.x; a1 = (float)a.y; a2 = (float)a.z;
    }
    int beg = rowptr[node], end = rowptr[node + 1];
    int j = beg;
    for (; j < end && (j & 3); ++j) {           // align to 16B
        half4n v = t4[ssrc[j]];
        a0 += (float)v.x; a1 += (float)v.y; a2 += (float)v.z;
    }
    for (; j + 8 <= end; j += 8) {
        int4n sA = __builtin_nontemporal_load(reinterpret_cast<const int4n*>(ssrc + j));
        int4n sB = __builtin_nontemporal_load(reinterpret_cast<const int4n*>(ssrc + j + 4));
        int s[8] = {sA.x, sA.y, sA.z, sA.w, sB.x, sB.y, sB.z, sB.w};
        half4n v[8];
#pragma unroll
        for (int k = 0; k < 8; ++k) v[k] = t4[s[k]];
#pragma unroll
        for (int k = 0; k < 8; ++k) {
            a0 += (float)v[k].x; a1 += (float)v[k].y; a2 += (float)v[k].z;
        }
    }
    for (; j < end; ++j) {
        half4n v = t4[ssrc[j]];
        a0 += (float)v.x; a1 += (float)v.y; a2 += (float)v.z;
    }
    float d = dinv[node];
    float p0 = a0 * d, p1 = a1 * d, p2 = a2 * d;
    _Float16* orow = t16 + (size_t)node * 16;
#pragma unroll
    for (int q = 0; q < 2; ++q) {
        half8n o;
#pragma unroll
        for (int r = 0; r < 8; ++r) {
            int jj = q * 8 + r;
            float h = fmaf(p0, sW[jj], fmaf(p1, sW[16 + jj], fmaf(p2, sW[32 + jj], sb[jj])));
            o[r] = (_Float16)(fmaxf(h, 0.f) * d);
        }
        *reinterpret_cast<half8n*>(orow + q * 8) = o;
    }
}

// ------- layer2: 16-wide fp16 gather (2 lanes/node x 16B) + fused W2/relu/W3 -------

__global__ void k_g16mm(const int* __restrict__ rowptr, const int* __restrict__ ssrc,
                        const _Float16* __restrict__ t16, const float* __restrict__ dinv,
                        const float* __restrict__ W2, const float* __restrict__ b2,
                        const float* __restrict__ W3, float2* __restrict__ t3, int n) {
    __shared__ float sW2[512];
    __shared__ float sb2[32];
    __shared__ float sW3[64];
    for (int i = threadIdx.x; i < 512; i += 256) sW2[i] = W2[i];
    if (threadIdx.x < 32) sb2[threadIdx.x] = b2[threadIdx.x];
    if (threadIdx.x < 64) sW3[threadIdx.x] = W3[threadIdx.x];
    __syncthreads();

    int i = blockIdx.x * blockDim.x + threadIdx.x;
    int node = i >> 1;
    int half = i & 1;        // lane owns feats half*8 .. half*8+7 (16 B)
    if (node >= n) return;   // pairs exit together
    int f0 = half * 8;

    float acc[8];
    {
        half8n v = *reinterpret_cast<const half8n*>(t16 + (size_t)node * 16 + f0);
#pragma unroll
        for (int c = 0; c < 8; ++c) acc[c] = (float)v[c];
    }
    int beg = rowptr[node], end = rowptr[node + 1];
    int j = beg;
    for (; j < end && (j & 3); ++j) {
        half8n v = *reinterpret_cast<const half8n*>(t16 + (size_t)ssrc[j] * 16 + f0);
#pragma unroll
        for (int c = 0; c < 8; ++c) acc[c] += (float)v[c];
    }
    for (; j + 8 <= end; j += 8) {
        int4n sA = __builtin_nontemporal_load(reinterpret_cast<const int4n*>(ssrc + j));
        int4n sB = __builtin_nontemporal_load(reinterpret_cast<const int4n*>(ssrc + j + 4));
        int s[8] = {sA.x, sA.y, sA.z, sA.w, sB.x, sB.y, sB.z, sB.w};
        half8n v[8];
#pragma unroll
        for (int k = 0; k < 8; ++k)
            v[k] = *reinterpret_cast<const half8n*>(t16 + (size_t)s[k] * 16 + f0);
#pragma unroll
        for (int k = 0; k < 8; ++k) {
#pragma unroll
            for (int c = 0; c < 8; ++c) acc[c] += (float)v[k][c];
        }
    }
    for (; j < end; ++j) {
        half8n v = *reinterpret_cast<const half8n*>(t16 + (size_t)ssrc[j] * 16 + f0);
#pragma unroll
        for (int c = 0; c < 8; ++c) acc[c] += (float)v[c];
    }
    float d = dinv[node];
    float q[8];
#pragma unroll
    for (int c = 0; c < 8; ++c) q[c] = acc[c] * d;   // u[f0..f0+7]

    // pair exchange: partner holds the other 8 feats
    float pq[8];
#pragma unroll
    for (int c = 0; c < 8; ++c) pq[c] = __shfl_xor(q[c], 1);

    float uu[16];
#pragma unroll
    for (int c = 0; c < 8; ++c) {
        uu[c]     = half ? pq[c] : q[c];   // u[0..7]
        uu[8 + c] = half ? q[c]  : pq[c];  // u[8..15]
    }

    // lane computes W2 columns half*16 .. half*16+15
    float t30 = 0.f, t31 = 0.f;
    int jbase = half * 16;
#pragma unroll
    for (int r = 0; r < 16; ++r) {
        int jj = jbase + r;
        float h = sb2[jj];
#pragma unroll
        for (int k = 0; k < 16; ++k) h = fmaf(uu[k], sW2[k * 32 + jj], h);
        h = fmaxf(h, 0.f);
        t30 = fmaf(h, sW3[jj * 2 + 0], t30);
        t31 = fmaf(h, sW3[jj * 2 + 1], t31);
    }
    t30 += __shfl_xor(t30, 1);
    t31 += __shfl_xor(t31, 1);
    if (half == 0) t3[node] = make_float2(t30 * d, t31 * d);
}

// ---------------- layer3: gather 2-wide + bias ----------------

__global__ void k_g2(const int* __restrict__ rowptr, const int* __restrict__ ssrc,
                     const float2* __restrict__ t3, const float* __restrict__ dinv,
                     const float* __restrict__ b3, float2* __restrict__ out, int n) {
    int node = blockIdx.x * blockDim.x + threadIdx.x;
    if (node >= n) return;
    float2 t = t3[node];
    float a0 = t.x, a1 = t.y;
    int beg = rowptr[node], end = rowptr[node + 1];
    int j = beg;
    for (; j < end && (j & 3); ++j) {
        float2 v = t3[ssrc[j]];
        a0 += v.x; a1 += v.y;
    }
    for (; j + 8 <= end; j += 8) {
        int4n sA = __builtin_nontemporal_load(reinterpret_cast<const int4n*>(ssrc + j));
        int4n sB = __builtin_nontemporal_load(reinterpret_cast<const int4n*>(ssrc + j + 4));
        int s[8] = {sA.x, sA.y, sA.z, sA.w, sB.x, sB.y, sB.z, sB.w};
        float2 v[8];
#pragma unroll
        for (int k = 0; k < 8; ++k) v[k] = t3[s[k]];
#pragma unroll
        for (int k = 0; k < 8; ++k) { a0 += v[k].x; a1 += v[k].y; }
    }
    for (; j < end; ++j) {
        float2 v = t3[ssrc[j]];
        a0 += v.x; a1 += v.y;
    }
    float d = dinv[node];
    out[node] = make_float2(fmaf(d, a0, b3[0]), fmaf(d, a1, b3[1]));
}

// ---------------- launch ----------------

static inline size_t align256(size_t x) { return (x + 255) & ~(size_t)255; }

extern "C" void kernel_launch(void* const* d_in, const int* in_sizes, int n_in,
                              void* d_out, int out_size, void* d_ws, size_t ws_size,
                              hipStream_t stream) {
    const float* x  = (const float*)d_in[0];
    const int*   ei = (const int*)d_in[1];
    const float* W1 = (const float*)d_in[2];
    const float* b1 = (const float*)d_in[3];
    const float* W2 = (const float*)d_in[4];
    const float* b2 = (const float*)d_in[5];
    const float* W3 = (const float*)d_in[6];
    const float* b3 = (const float*)d_in[7];
    float2* out = (float2*)d_out;

    const int* src = ei;
    const int* dst = ei + NED;

    char* p = (char*)d_ws;
    float* dinv   = (float*)p; p += align256(sizeof(float) * (size_t)NND);
    int*   rowptr = (int*)p;   p += align256(sizeof(int) * (size_t)(NND + 1));
    int*   excl   = (int*)p;   p += align256(sizeof(int) * (size_t)(SCAN_N + 1));
    int*   bsums  = (int*)p;   p += align256(sizeof(int) * 128);
    int*   ssrc   = (int*)p;   p += align256(sizeof(int) * (size_t)NED);
    half4n* t4    = (half4n*)p; p += align256(sizeof(half4n) * (size_t)NND);
    float2* t3    = (float2*)p; p += align256(sizeof(float2) * (size_t)NND);
    // region shared by tmp (dead after k_bucket) and t16 (written after)
    char*  q      = p;         p += align256(sizeof(int) * (size_t)NED);
    int*   tmp    = (int*)q;
    _Float16* t16 = (_Float16*)q;                                // [NND][16] fp16

    const int B = 256;
    const int gridN = (NND + B - 1) / B;
    const int grid2N = (NND * 2 + B - 1) / B;

    // ---- CSR build (scan2 folded into part/bucket; scan3 folded away) ----
    k_hist<<<NCHUNK, B, 0, stream>>>(dst, excl);
    k_scan1<<<NSB, 256, 0, stream>>>(excl, excl, bsums, SCAN_N);
    k_part<<<NCHUNK, B, 0, stream>>>(src, dst, excl, bsums, tmp);
    k_bucket<<<NB, B, 0, stream>>>(excl, bsums, tmp, ssrc, rowptr, dinv, x, t4);

    // ---- layer 1: aggregate fp16 4-wide, fused 3->16, fp16 table out ----
    k_g4mm1<<<gridN, B, 0, stream>>>(rowptr, ssrc, t4, dinv, W1, b1, t16, NND);

    // ---- layer 2: 16-wide fp16 gather (2 lanes/node) + fused W2/relu/W3 -> t3 ----
    k_g16mm<<<grid2N, B, 0, stream>>>(rowptr, ssrc, t16, dinv, W2, b2, W3, t3, NND);

    // ---- layer 3: gather 2-wide ----
    k_g2<<<gridN, B, 0, stream>>>(rowptr, ssrc, t3, dinv, b3, out, NND);
}

// Round 14
// 150.491 us; speedup vs baseline: 1.1449x; 1.1449x over previous
//
#include <hip/hip_runtime.h>

static constexpr int NND = 100000;        // nodes
static constexpr int NED = 3200000;       // edges (before self-loops)
static constexpr int NB  = (NND + 255) / 256;   // 391 buckets of 256 nodes
static constexpr int NCHUNK = 256;              // edge chunks
static constexpr int EPC = NED / NCHUNK;        // 12500 edges per chunk (=3125*4)
static constexpr int SCAN_N = NB * NCHUNK;      // 100096
static constexpr int NSB = (SCAN_N + 1023) / 1024;  // 98 scan blocks
static constexpr int CAP = 12288;               // LDS cache entries for a bucket run (48 KB)

typedef int int4n __attribute__((ext_vector_type(4)));        // native vec for nontemporal builtins
typedef _Float16 half4n __attribute__((ext_vector_type(4)));  // 8 B fp16 quad
typedef _Float16 half8n __attribute__((ext_vector_type(8)));  // 16 B fp16 oct

// ---------------- partition pass 1: per-(chunk,bucket) histogram ----------------

__global__ void k_hist(const int* __restrict__ dst, int* __restrict__ counts) {
    __shared__ int h[NB];
    for (int i = threadIdx.x; i < NB; i += 256) h[i] = 0;
    __syncthreads();
    int c = blockIdx.x;
    const int4n* d4 = reinterpret_cast<const int4n*>(dst + c * EPC);
    for (int i = threadIdx.x; i < EPC / 4; i += 256) {
        int4n v = d4[i];
        atomicAdd(&h[v.x >> 8], 1);
        atomicAdd(&h[v.y >> 8], 1);
        atomicAdd(&h[v.z >> 8], 1);
        atomicAdd(&h[v.w >> 8], 1);
    }
    __syncthreads();
    for (int b = threadIdx.x; b < NB; b += 256)
        counts[b * NCHUNK + c] = h[b];   // bucket-major for the scan
}

// ---------------- scan (exclusive), 1024 elems/block ----------------

__global__ void k_scan1(const int* __restrict__ in, int* __restrict__ excl,
                        int* __restrict__ blockSums, int n) {
    __shared__ int lds[256];
    int tid = threadIdx.x;
    int base = blockIdx.x * 1024 + tid * 4;
    int v[4]; int sum = 0;
#pragma unroll
    for (int k = 0; k < 4; ++k) { int idx = base + k; v[k] = (idx < n) ? in[idx] : 0; sum += v[k]; }
    lds[tid] = sum; __syncthreads();
    for (int off = 1; off < 256; off <<= 1) {
        int x = lds[tid];
        int y = (tid >= off) ? lds[tid - off] : 0;
        __syncthreads();
        lds[tid] = x + y;
        __syncthreads();
    }
    int run = lds[tid] - sum;
#pragma unroll
    for (int k = 0; k < 4; ++k) { int idx = base + k; if (idx < n) excl[idx] = run; run += v[k]; }
    if (tid == 0) blockSums[blockIdx.x] = lds[255];
}

__global__ void k_scan2(int* __restrict__ blockSums, int nb) {  // single block, 128 thr
    __shared__ int lds[128];
    int tid = threadIdx.x;
    int v = (tid < nb) ? blockSums[tid] : 0;
    lds[tid] = v; __syncthreads();
    for (int off = 1; off < 128; off <<= 1) {
        int x = lds[tid];
        int y = (tid >= off) ? lds[tid - off] : 0;
        __syncthreads();
        lds[tid] = x + y;
        __syncthreads();
    }
    if (tid < nb) blockSums[tid] = lds[tid] - v;
}

// ---------------- partition pass 2: scatter into bucket runs ----------------
// pack = src | (dst&255)<<20   (src < 2^20); global offset = excl[i] + bsums[i>>10]

__global__ void k_part(const int* __restrict__ src, const int* __restrict__ dst,
                       const int* __restrict__ excl, const int* __restrict__ bsums,
                       int* __restrict__ tmp) {
    __shared__ int cur[NB];
    int c = blockIdx.x;
    for (int b = threadIdx.x; b < NB; b += 256) {
        int i = b * NCHUNK + c;
        cur[b] = excl[i] + bsums[i >> 10];
    }
    __syncthreads();
    const int4n* s4 = reinterpret_cast<const int4n*>(src + c * EPC);
    const int4n* d4 = reinterpret_cast<const int4n*>(dst + c * EPC);
    for (int i = threadIdx.x; i < EPC / 4; i += 256) {
        int4n sv = __builtin_nontemporal_load(&s4[i]);   // src/dst: genuinely last-read here
        int4n dv = __builtin_nontemporal_load(&d4[i]);
        int ss[4] = {sv.x, sv.y, sv.z, sv.w};
        int dd[4] = {dv.x, dv.y, dv.z, dv.w};
#pragma unroll
        for (int k = 0; k < 4; ++k) {
            int b = dd[k] >> 8;
            int pos = atomicAdd(&cur[b], 1);
            tmp[pos] = ss[k] | ((dd[k] & 255) << 20);    // PLAIN store: L2 write-combines runs
        }
    }
}

// ------- per-bucket: deg/dinv/rowptr + CSR fill + fused layer-1 prep -------
// Bucket's tmp run is cached in LDS once (avg 8184 entries, CAP=12288 w/ fallback),
// so tmp is read from global exactly once instead of twice.

__global__ void k_bucket(const int* __restrict__ excl, const int* __restrict__ bsums,
                         const int* __restrict__ tmp,
                         int* __restrict__ ssrc, int* __restrict__ rowptr,
                         float* __restrict__ dinv, const float* __restrict__ x,
                         half4n* __restrict__ t4) {
    __shared__ int cache[CAP];
    __shared__ int cnt[256];
    __shared__ int lds[256];
    int b = blockIdx.x, t = threadIdx.x;
    int i0 = b * NCHUNK;
    int start = excl[i0] + bsums[i0 >> 10];
    int end;
    if (b == NB - 1) end = NED;
    else { int i1 = (b + 1) * NCHUNK; end = excl[i1] + bsums[i1 >> 10]; }
    int run = end - start;
    int cached = run < CAP ? run : CAP;
    for (int i = t; i < cached; i += 256) cache[i] = tmp[start + i];
    cnt[t] = 0;
    __syncthreads();
    for (int i = t; i < run; i += 256) {
        int p = (i < CAP) ? cache[i] : tmp[start + i];
        atomicAdd(&cnt[p >> 20], 1);
    }
    __syncthreads();
    int v = cnt[t];
    lds[t] = v; __syncthreads();
    for (int off = 1; off < 256; off <<= 1) {
        int xv = lds[t];
        int y = (t >= off) ? lds[t - off] : 0;
        __syncthreads();
        lds[t] = xv + y;
        __syncthreads();
    }
    int node = b * 256 + t;
    int rp = start + lds[t] - v;
    if (node < NND) {
        rowptr[node] = rp;
        float d = rsqrtf((float)(v + 1));  // +1 self-loop
        dinv[node] = d;
        const float* xr = x + (size_t)node * 3;   // fused layer-1 prep (fp16 table)
        half4n o;
        o.x = (_Float16)(xr[0] * d); o.y = (_Float16)(xr[1] * d);
        o.z = (_Float16)(xr[2] * d); o.w = (_Float16)0.f;
        t4[node] = o;
    }
    if (b == 0 && t == 0) rowptr[NND] = NED;
    cnt[t] = rp;
    __syncthreads();
    for (int i = t; i < run; i += 256) {
        int p = (i < CAP) ? cache[i] : tmp[start + i];
        int pos = atomicAdd(&cnt[p >> 20], 1);
        ssrc[pos] = p & 0xFFFFF;
    }
}

// ------- layer1: gather fp16 4-wide + fused 3->16 matmul, fp16 table out -------

__global__ void k_g4mm1(const int* __restrict__ rowptr, const int* __restrict__ ssrc,
                        const half4n* __restrict__ t4, const float* __restrict__ dinv,
                        const float* __restrict__ W1, const float* __restrict__ b1,
                        _Float16* __restrict__ t16, int n) {
    __shared__ float sW[48];
    __shared__ float sb[16];
    if (threadIdx.x < 48) sW[threadIdx.x] = W1[threadIdx.x];
    if (threadIdx.x < 16) sb[threadIdx.x] = b1[threadIdx.x];
    __syncthreads();
    int node = blockIdx.x * blockDim.x + threadIdx.x;
    if (node >= n) return;

    float a0, a1, a2;
    {
        half4n a = t4[node];
        a0 = (float)a.x; a1 = (float)a.y; a2 = (float)a.z;
    }
    int beg = rowptr[node], end = rowptr[node + 1];
    constexpr int U = 8;
    int j = beg;
    for (; j + U <= end; j += U) {
        int s[U];
#pragma unroll
        for (int k = 0; k < U; ++k) s[k] = ssrc[j + k];
        half4n v[U];
#pragma unroll
        for (int k = 0; k < U; ++k) v[k] = t4[s[k]];
#pragma unroll
        for (int k = 0; k < U; ++k) {
            a0 += (float)v[k].x; a1 += (float)v[k].y; a2 += (float)v[k].z;
        }
    }
    for (; j < end; ++j) {
        half4n v = t4[ssrc[j]];
        a0 += (float)v.x; a1 += (float)v.y; a2 += (float)v.z;
    }
    float d = dinv[node];
    float p0 = a0 * d, p1 = a1 * d, p2 = a2 * d;
    _Float16* orow = t16 + (size_t)node * 16;
#pragma unroll
    for (int q = 0; q < 2; ++q) {
        half8n o;
#pragma unroll
        for (int r = 0; r < 8; ++r) {
            int jj = q * 8 + r;
            float h = fmaf(p0, sW[jj], fmaf(p1, sW[16 + jj], fmaf(p2, sW[32 + jj], sb[jj])));
            o[r] = (_Float16)(fmaxf(h, 0.f) * d);
        }
        *reinterpret_cast<half8n*>(orow + q * 8) = o;
    }
}

// ------- layer2: 16-wide fp16 gather (2 lanes/node x 16B) + fused W2/relu/W3 -------

__global__ void k_g16mm(const int* __restrict__ rowptr, const int* __restrict__ ssrc,
                        const _Float16* __restrict__ t16, const float* __restrict__ dinv,
                        const float* __restrict__ W2, const float* __restrict__ b2,
                        const float* __restrict__ W3, float2* __restrict__ t3, int n) {
    __shared__ float sW2[512];
    __shared__ float sb2[32];
    __shared__ float sW3[64];
    for (int i = threadIdx.x; i < 512; i += 256) sW2[i] = W2[i];
    if (threadIdx.x < 32) sb2[threadIdx.x] = b2[threadIdx.x];
    if (threadIdx.x < 64) sW3[threadIdx.x] = W3[threadIdx.x];
    __syncthreads();

    constexpr int U = 8;
    int i = blockIdx.x * blockDim.x + threadIdx.x;
    int node = i >> 1;
    int half = i & 1;        // lane owns feats half*8 .. half*8+7 (16 B)
    if (node >= n) return;   // pairs exit together
    int f0 = half * 8;

    float acc[8];
    {
        half8n v = *reinterpret_cast<const half8n*>(t16 + (size_t)node * 16 + f0);
#pragma unroll
        for (int c = 0; c < 8; ++c) acc[c] = (float)v[c];
    }
    int beg = rowptr[node], end = rowptr[node + 1];
    int j = beg;
    for (; j + U <= end; j += U) {
        int s[U];
#pragma unroll
        for (int k = 0; k < U; ++k) s[k] = ssrc[j + k];
        half8n v[U];
#pragma unroll
        for (int k = 0; k < U; ++k)
            v[k] = *reinterpret_cast<const half8n*>(t16 + (size_t)s[k] * 16 + f0);
#pragma unroll
        for (int k = 0; k < U; ++k) {
#pragma unroll
            for (int c = 0; c < 8; ++c) acc[c] += (float)v[k][c];
        }
    }
    for (; j < end; ++j) {
        half8n v = *reinterpret_cast<const half8n*>(t16 + (size_t)ssrc[j] * 16 + f0);
#pragma unroll
        for (int c = 0; c < 8; ++c) acc[c] += (float)v[c];
    }
    float d = dinv[node];
    float q[8];
#pragma unroll
    for (int c = 0; c < 8; ++c) q[c] = acc[c] * d;   // u[f0..f0+7]

    // pair exchange: partner holds the other 8 feats
    float pq[8];
#pragma unroll
    for (int c = 0; c < 8; ++c) pq[c] = __shfl_xor(q[c], 1);

    float uu[16];
#pragma unroll
    for (int c = 0; c < 8; ++c) {
        uu[c]     = half ? pq[c] : q[c];   // u[0..7]
        uu[8 + c] = half ? q[c]  : pq[c];  // u[8..15]
    }

    // lane computes W2 columns half*16 .. half*16+15
    float t30 = 0.f, t31 = 0.f;
    int jbase = half * 16;
#pragma unroll
    for (int r = 0; r < 16; ++r) {
        int jj = jbase + r;
        float h = sb2[jj];
#pragma unroll
        for (int k = 0; k < 16; ++k) h = fmaf(uu[k], sW2[k * 32 + jj], h);
        h = fmaxf(h, 0.f);
        t30 = fmaf(h, sW3[jj * 2 + 0], t30);
        t31 = fmaf(h, sW3[jj * 2 + 1], t31);
    }
    t30 += __shfl_xor(t30, 1);
    t31 += __shfl_xor(t31, 1);
    if (half == 0) t3[node] = make_float2(t30 * d, t31 * d);
}

// ---------------- layer3: gather 2-wide + bias ----------------

__global__ void k_g2(const int* __restrict__ rowptr, const int* __restrict__ ssrc,
                     const float2* __restrict__ t3, const float* __restrict__ dinv,
                     const float* __restrict__ b3, float2* __restrict__ out, int n) {
    constexpr int U = 8;
    int node = blockIdx.x * blockDim.x + threadIdx.x;
    if (node >= n) return;
    float2 t = t3[node];
    float a0 = t.x, a1 = t.y;
    int beg = rowptr[node], end = rowptr[node + 1];
    int j = beg;
    for (; j + U <= end; j += U) {
        int s[U];
#pragma unroll
        for (int k = 0; k < U; ++k) s[k] = ssrc[j + k];
        float2 v[U];
#pragma unroll
        for (int k = 0; k < U; ++k) v[k] = t3[s[k]];
#pragma unroll
        for (int k = 0; k < U; ++k) { a0 += v[k].x; a1 += v[k].y; }
    }
    for (; j < end; ++j) {
        float2 v = t3[ssrc[j]];
        a0 += v.x; a1 += v.y;
    }
    float d = dinv[node];
    out[node] = make_float2(fmaf(d, a0, b3[0]), fmaf(d, a1, b3[1]));
}

// ---------------- launch ----------------

static inline size_t align256(size_t x) { return (x + 255) & ~(size_t)255; }

extern "C" void kernel_launch(void* const* d_in, const int* in_sizes, int n_in,
                              void* d_out, int out_size, void* d_ws, size_t ws_size,
                              hipStream_t stream) {
    const float* x  = (const float*)d_in[0];
    const int*   ei = (const int*)d_in[1];
    const float* W1 = (const float*)d_in[2];
    const float* b1 = (const float*)d_in[3];
    const float* W2 = (const float*)d_in[4];
    const float* b2 = (const float*)d_in[5];
    const float* W3 = (const float*)d_in[6];
    const float* b3 = (const float*)d_in[7];
    float2* out = (float2*)d_out;

    const int* src = ei;
    const int* dst = ei + NED;

    char* p = (char*)d_ws;
    float* dinv   = (float*)p; p += align256(sizeof(float) * (size_t)NND);
    int*   rowptr = (int*)p;   p += align256(sizeof(int) * (size_t)(NND + 1));
    int*   excl   = (int*)p;   p += align256(sizeof(int) * (size_t)(SCAN_N + 1));
    int*   bsums  = (int*)p;   p += align256(sizeof(int) * 128);
    int*   ssrc   = (int*)p;   p += align256(sizeof(int) * (size_t)NED);
    half4n* t4    = (half4n*)p; p += align256(sizeof(half4n) * (size_t)NND);
    float2* t3    = (float2*)p; p += align256(sizeof(float2) * (size_t)NND);
    // region shared by tmp (dead after k_bucket) and t16 (written after)
    char*  q      = p;         p += align256(sizeof(int) * (size_t)NED);
    int*   tmp    = (int*)q;
    _Float16* t16 = (_Float16*)q;                                // [NND][16] fp16

    const int B = 256;
    const int gridN = (NND + B - 1) / B;
    const int grid2N = (NND * 2 + B - 1) / B;

    // ---- CSR build (scan3 folded into consumers; scan2 separate tiny kernel) ----
    k_hist<<<NCHUNK, B, 0, stream>>>(dst, excl);
    k_scan1<<<NSB, 256, 0, stream>>>(excl, excl, bsums, SCAN_N);
    k_scan2<<<1, 128, 0, stream>>>(bsums, NSB);
    k_part<<<NCHUNK, B, 0, stream>>>(src, dst, excl, bsums, tmp);
    k_bucket<<<NB, B, 0, stream>>>(excl, bsums, tmp, ssrc, rowptr, dinv, x, t4);

    // ---- layer 1: aggregate fp16 4-wide, fused 3->16, fp16 table out ----
    k_g4mm1<<<gridN, B, 0, stream>>>(rowptr, ssrc, t4, dinv, W1, b1, t16, NND);

    // ---- layer 2: 16-wide fp16 gather (2 lanes/node) + fused W2/relu/W3 -> t3 ----
    k_g16mm<<<grid2N, B, 0, stream>>>(rowptr, ssrc, t16, dinv, W2, b2, W3, t3, NND);

    // ---- layer 3: gather 2-wide ----
    k_g2<<<gridN, B, 0, stream>>>(rowptr, ssrc, t3, dinv, b3, out, NND);
}

// Round 15
// 149.000 us; speedup vs baseline: 1.1564x; 1.0100x over previous
//
#include <hip/hip_runtime.h>

static constexpr int NND = 100000;        // nodes
static constexpr int NED = 3200000;       // edges (before self-loops)
static constexpr int NB  = (NND + 255) / 256;   // 391 buckets of 256 nodes
static constexpr int NCHUNK = 256;              // edge chunks
static constexpr int EPC = NED / NCHUNK;        // 12500 edges per chunk (=3125*4)
static constexpr int SCAN_N = NB * NCHUNK;      // 100096
static constexpr int NSB = (SCAN_N + 1023) / 1024;  // 98 scan blocks
static constexpr int CAP = 12288;               // LDS cache entries for a bucket run (48 KB)

typedef int int4n __attribute__((ext_vector_type(4)));        // native vec for nontemporal builtins
typedef _Float16 half4n __attribute__((ext_vector_type(4)));  // 8 B fp16 quad
typedef _Float16 half8n __attribute__((ext_vector_type(8)));  // 16 B fp16 oct

// ---------------- partition pass 1: per-(chunk,bucket) histogram ----------------

__global__ void k_hist(const int* __restrict__ dst, int* __restrict__ counts) {
    __shared__ int h[NB];
    for (int i = threadIdx.x; i < NB; i += 256) h[i] = 0;
    __syncthreads();
    int c = blockIdx.x;
    const int4n* d4 = reinterpret_cast<const int4n*>(dst + c * EPC);
    for (int i = threadIdx.x; i < EPC / 4; i += 256) {
        int4n v = d4[i];
        atomicAdd(&h[v.x >> 8], 1);
        atomicAdd(&h[v.y >> 8], 1);
        atomicAdd(&h[v.z >> 8], 1);
        atomicAdd(&h[v.w >> 8], 1);
    }
    __syncthreads();
    for (int b = threadIdx.x; b < NB; b += 256)
        counts[b * NCHUNK + c] = h[b];   // bucket-major for the scan
}

// ---------------- scan (exclusive within 1024-chunk), raw chunk sums -> bsums ----------------

__global__ void k_scan1(const int* __restrict__ in, int* __restrict__ excl,
                        int* __restrict__ blockSums, int n) {
    __shared__ int lds[256];
    int tid = threadIdx.x;
    int base = blockIdx.x * 1024 + tid * 4;
    int v[4]; int sum = 0;
#pragma unroll
    for (int k = 0; k < 4; ++k) { int idx = base + k; v[k] = (idx < n) ? in[idx] : 0; sum += v[k]; }
    lds[tid] = sum; __syncthreads();
    for (int off = 1; off < 256; off <<= 1) {
        int x = lds[tid];
        int y = (tid >= off) ? lds[tid - off] : 0;
        __syncthreads();
        lds[tid] = x + y;
        __syncthreads();
    }
    int run = lds[tid] - sum;
#pragma unroll
    for (int k = 0; k < 4; ++k) { int idx = base + k; if (idx < n) excl[idx] = run; run += v[k]; }
    if (tid == 0) blockSums[blockIdx.x] = lds[255];
}

// in-block exclusive scan of the 98 raw block sums (replaces k_scan2; proven in R12)
__device__ __forceinline__ void scan_bsums(const int* __restrict__ bsums, int* sbs, int t) {
    int orig = 0;
    if (t < 128) { orig = (t < NSB) ? bsums[t] : 0; sbs[t] = orig; }
    __syncthreads();
    for (int off = 1; off < 128; off <<= 1) {
        int v = 0;
        if (t < 128) { v = sbs[t]; if (t >= off) v += sbs[t - off]; }
        __syncthreads();
        if (t < 128) sbs[t] = v;
        __syncthreads();
    }
    if (t < 128) sbs[t] -= orig;   // exclusive
    __syncthreads();
}

// ---------------- partition pass 2: scatter into bucket runs ----------------
// pack = src | (dst&255)<<20   (src < 2^20); global offset = excl[i] + sbs[i>>10]

__global__ void k_part(const int* __restrict__ src, const int* __restrict__ dst,
                       const int* __restrict__ excl, const int* __restrict__ bsums,
                       int* __restrict__ tmp) {
    __shared__ int cur[NB];
    __shared__ int sbs[128];
    int c = blockIdx.x, t = threadIdx.x;
    scan_bsums(bsums, sbs, t);
    for (int b = t; b < NB; b += 256) {
        int i = b * NCHUNK + c;
        cur[b] = excl[i] + sbs[i >> 10];
    }
    __syncthreads();
    const int4n* s4 = reinterpret_cast<const int4n*>(src + c * EPC);
    const int4n* d4 = reinterpret_cast<const int4n*>(dst + c * EPC);
    for (int i = t; i < EPC / 4; i += 256) {
        int4n sv = __builtin_nontemporal_load(&s4[i]);   // src/dst: genuinely last-read here
        int4n dv = __builtin_nontemporal_load(&d4[i]);
        int ss[4] = {sv.x, sv.y, sv.z, sv.w};
        int dd[4] = {dv.x, dv.y, dv.z, dv.w};
#pragma unroll
        for (int k = 0; k < 4; ++k) {
            int b = dd[k] >> 8;
            int pos = atomicAdd(&cur[b], 1);
            tmp[pos] = ss[k] | ((dd[k] & 255) << 20);    // PLAIN store: L2 write-combines runs
        }
    }
}

// ------- per-bucket: deg/dinv/rowptr + CSR fill + fused layer-1 prep -------
// Bucket's tmp run cached in LDS once (avg 8184 entries, CAP=12288 w/ fallback).

__global__ void k_bucket(const int* __restrict__ excl, const int* __restrict__ bsums,
                         const int* __restrict__ tmp,
                         int* __restrict__ ssrc, int* __restrict__ rowptr,
                         float* __restrict__ dinv, const float* __restrict__ x,
                         half4n* __restrict__ t4) {
    __shared__ int cache[CAP];
    __shared__ int cnt[256];
    __shared__ int lds[256];
    __shared__ int sbs[128];
    int b = blockIdx.x, t = threadIdx.x;
    scan_bsums(bsums, sbs, t);
    int i0 = b * NCHUNK;
    int start = excl[i0] + sbs[i0 >> 10];
    int end;
    if (b == NB - 1) end = NED;
    else { int i1 = (b + 1) * NCHUNK; end = excl[i1] + sbs[i1 >> 10]; }
    int run = end - start;
    int cached = run < CAP ? run : CAP;
    for (int i = t; i < cached; i += 256) cache[i] = tmp[start + i];
    cnt[t] = 0;
    __syncthreads();
    for (int i = t; i < run; i += 256) {
        int p = (i < CAP) ? cache[i] : tmp[start + i];
        atomicAdd(&cnt[p >> 20], 1);
    }
    __syncthreads();
    int v = cnt[t];
    lds[t] = v; __syncthreads();
    for (int off = 1; off < 256; off <<= 1) {
        int xv = lds[t];
        int y = (t >= off) ? lds[t - off] : 0;
        __syncthreads();
        lds[t] = xv + y;
        __syncthreads();
    }
    int node = b * 256 + t;
    int rp = start + lds[t] - v;
    if (node < NND) {
        rowptr[node] = rp;
        float d = rsqrtf((float)(v + 1));  // +1 self-loop
        dinv[node] = d;
        const float* xr = x + (size_t)node * 3;   // fused layer-1 prep (fp16 table)
        half4n o;
        o.x = (_Float16)(xr[0] * d); o.y = (_Float16)(xr[1] * d);
        o.z = (_Float16)(xr[2] * d); o.w = (_Float16)0.f;
        t4[node] = o;
    }
    if (b == 0 && t == 0) rowptr[NND] = NED;
    cnt[t] = rp;
    __syncthreads();
    for (int i = t; i < run; i += 256) {
        int p = (i < CAP) ? cache[i] : tmp[start + i];
        int pos = atomicAdd(&cnt[p >> 20], 1);
        ssrc[pos] = p & 0xFFFFF;
    }
}

// ------- layer1: gather fp16 4-wide + fused 3->16 matmul, fp16 table out -------
// ssrc index stream software-pipelined one U-batch ahead of the row gathers.

__global__ void k_g4mm1(const int* __restrict__ rowptr, const int* __restrict__ ssrc,
                        const half4n* __restrict__ t4, const float* __restrict__ dinv,
                        const float* __restrict__ W1, const float* __restrict__ b1,
                        _Float16* __restrict__ t16, int n) {
    __shared__ float sW[48];
    __shared__ float sb[16];
    if (threadIdx.x < 48) sW[threadIdx.x] = W1[threadIdx.x];
    if (threadIdx.x < 16) sb[threadIdx.x] = b1[threadIdx.x];
    __syncthreads();
    int node = blockIdx.x * blockDim.x + threadIdx.x;
    if (node >= n) return;

    float a0, a1, a2;
    {
        half4n a = t4[node];
        a0 = (float)a.x; a1 = (float)a.y; a2 = (float)a.z;
    }
    int beg = rowptr[node], end = rowptr[node + 1];
    constexpr int U = 8;
    int j = beg;
    if (j + U <= end) {
        int sc[U];
#pragma unroll
        for (int k = 0; k < U; ++k) sc[k] = ssrc[j + k];
        for (; j + 2 * U <= end; j += U) {
            int sn[U];
#pragma unroll
            for (int k = 0; k < U; ++k) sn[k] = ssrc[j + U + k];
            half4n v[U];
#pragma unroll
            for (int k = 0; k < U; ++k) v[k] = t4[sc[k]];
#pragma unroll
            for (int k = 0; k < U; ++k) {
                a0 += (float)v[k].x; a1 += (float)v[k].y; a2 += (float)v[k].z;
            }
#pragma unroll
            for (int k = 0; k < U; ++k) sc[k] = sn[k];
        }
        half4n v[U];
#pragma unroll
        for (int k = 0; k < U; ++k) v[k] = t4[sc[k]];
#pragma unroll
        for (int k = 0; k < U; ++k) {
            a0 += (float)v[k].x; a1 += (float)v[k].y; a2 += (float)v[k].z;
        }
        j += U;
    }
    for (; j < end; ++j) {
        half4n v = t4[ssrc[j]];
        a0 += (float)v.x; a1 += (float)v.y; a2 += (float)v.z;
    }
    float d = dinv[node];
    float p0 = a0 * d, p1 = a1 * d, p2 = a2 * d;
    _Float16* orow = t16 + (size_t)node * 16;
#pragma unroll
    for (int q = 0; q < 2; ++q) {
        half8n o;
#pragma unroll
        for (int r = 0; r < 8; ++r) {
            int jj = q * 8 + r;
            float h = fmaf(p0, sW[jj], fmaf(p1, sW[16 + jj], fmaf(p2, sW[32 + jj], sb[jj])));
            o[r] = (_Float16)(fmaxf(h, 0.f) * d);
        }
        *reinterpret_cast<half8n*>(orow + q * 8) = o;
    }
}

// ------- layer2: 16-wide fp16 gather (2 lanes/node x 16B) + fused W2/relu/W3 -------

__global__ void k_g16mm(const int* __restrict__ rowptr, const int* __restrict__ ssrc,
                        const _Float16* __restrict__ t16, const float* __restrict__ dinv,
                        const float* __restrict__ W2, const float* __restrict__ b2,
                        const float* __restrict__ W3, float2* __restrict__ t3, int n) {
    __shared__ float sW2[512];
    __shared__ float sb2[32];
    __shared__ float sW3[64];
    for (int i = threadIdx.x; i < 512; i += 256) sW2[i] = W2[i];
    if (threadIdx.x < 32) sb2[threadIdx.x] = b2[threadIdx.x];
    if (threadIdx.x < 64) sW3[threadIdx.x] = W3[threadIdx.x];
    __syncthreads();

    constexpr int U = 8;
    int i = blockIdx.x * blockDim.x + threadIdx.x;
    int node = i >> 1;
    int half = i & 1;        // lane owns feats half*8 .. half*8+7 (16 B)
    if (node >= n) return;   // pairs exit together
    int f0 = half * 8;

    float acc[8];
    {
        half8n v = *reinterpret_cast<const half8n*>(t16 + (size_t)node * 16 + f0);
#pragma unroll
        for (int c = 0; c < 8; ++c) acc[c] = (float)v[c];
    }
    int beg = rowptr[node], end = rowptr[node + 1];
    int j = beg;
    if (j + U <= end) {
        int sc[U];
#pragma unroll
        for (int k = 0; k < U; ++k) sc[k] = ssrc[j + k];
        for (; j + 2 * U <= end; j += U) {
            int sn[U];
#pragma unroll
            for (int k = 0; k < U; ++k) sn[k] = ssrc[j + U + k];
            half8n v[U];
#pragma unroll
            for (int k = 0; k < U; ++k)
                v[k] = *reinterpret_cast<const half8n*>(t16 + (size_t)sc[k] * 16 + f0);
#pragma unroll
            for (int k = 0; k < U; ++k) {
#pragma unroll
                for (int c = 0; c < 8; ++c) acc[c] += (float)v[k][c];
            }
#pragma unroll
            for (int k = 0; k < U; ++k) sc[k] = sn[k];
        }
        half8n v[U];
#pragma unroll
        for (int k = 0; k < U; ++k)
            v[k] = *reinterpret_cast<const half8n*>(t16 + (size_t)sc[k] * 16 + f0);
#pragma unroll
        for (int k = 0; k < U; ++k) {
#pragma unroll
            for (int c = 0; c < 8; ++c) acc[c] += (float)v[k][c];
        }
        j += U;
    }
    for (; j < end; ++j) {
        half8n v = *reinterpret_cast<const half8n*>(t16 + (size_t)ssrc[j] * 16 + f0);
#pragma unroll
        for (int c = 0; c < 8; ++c) acc[c] += (float)v[c];
    }
    float d = dinv[node];
    float q[8];
#pragma unroll
    for (int c = 0; c < 8; ++c) q[c] = acc[c] * d;   // u[f0..f0+7]

    // pair exchange: partner holds the other 8 feats
    float pq[8];
#pragma unroll
    for (int c = 0; c < 8; ++c) pq[c] = __shfl_xor(q[c], 1);

    float uu[16];
#pragma unroll
    for (int c = 0; c < 8; ++c) {
        uu[c]     = half ? pq[c] : q[c];   // u[0..7]
        uu[8 + c] = half ? q[c]  : pq[c];  // u[8..15]
    }

    // lane computes W2 columns half*16 .. half*16+15
    float t30 = 0.f, t31 = 0.f;
    int jbase = half * 16;
#pragma unroll
    for (int r = 0; r < 16; ++r) {
        int jj = jbase + r;
        float h = sb2[jj];
#pragma unroll
        for (int k = 0; k < 16; ++k) h = fmaf(uu[k], sW2[k * 32 + jj], h);
        h = fmaxf(h, 0.f);
        t30 = fmaf(h, sW3[jj * 2 + 0], t30);
        t31 = fmaf(h, sW3[jj * 2 + 1], t31);
    }
    t30 += __shfl_xor(t30, 1);
    t31 += __shfl_xor(t31, 1);
    if (half == 0) t3[node] = make_float2(t30 * d, t31 * d);
}

// ---------------- layer3: gather 2-wide + bias ----------------

__global__ void k_g2(const int* __restrict__ rowptr, const int* __restrict__ ssrc,
                     const float2* __restrict__ t3, const float* __restrict__ dinv,
                     const float* __restrict__ b3, float2* __restrict__ out, int n) {
    constexpr int U = 8;
    int node = blockIdx.x * blockDim.x + threadIdx.x;
    if (node >= n) return;
    float2 t = t3[node];
    float a0 = t.x, a1 = t.y;
    int beg = rowptr[node], end = rowptr[node + 1];
    int j = beg;
    if (j + U <= end) {
        int sc[U];
#pragma unroll
        for (int k = 0; k < U; ++k) sc[k] = ssrc[j + k];
        for (; j + 2 * U <= end; j += U) {
            int sn[U];
#pragma unroll
            for (int k = 0; k < U; ++k) sn[k] = ssrc[j + U + k];
            float2 v[U];
#pragma unroll
            for (int k = 0; k < U; ++k) v[k] = t3[sc[k]];
#pragma unroll
            for (int k = 0; k < U; ++k) { a0 += v[k].x; a1 += v[k].y; }
#pragma unroll
            for (int k = 0; k < U; ++k) sc[k] = sn[k];
        }
        float2 v[U];
#pragma unroll
        for (int k = 0; k < U; ++k) v[k] = t3[sc[k]];
#pragma unroll
        for (int k = 0; k < U; ++k) { a0 += v[k].x; a1 += v[k].y; }
        j += U;
    }
    for (; j < end; ++j) {
        float2 v = t3[ssrc[j]];
        a0 += v.x; a1 += v.y;
    }
    float d = dinv[node];
    out[node] = make_float2(fmaf(d, a0, b3[0]), fmaf(d, a1, b3[1]));
}

// ---------------- launch ----------------

static inline size_t align256(size_t x) { return (x + 255) & ~(size_t)255; }

extern "C" void kernel_launch(void* const* d_in, const int* in_sizes, int n_in,
                              void* d_out, int out_size, void* d_ws, size_t ws_size,
                              hipStream_t stream) {
    const float* x  = (const float*)d_in[0];
    const int*   ei = (const int*)d_in[1];
    const float* W1 = (const float*)d_in[2];
    const float* b1 = (const float*)d_in[3];
    const float* W2 = (const float*)d_in[4];
    const float* b2 = (const float*)d_in[5];
    const float* W3 = (const float*)d_in[6];
    const float* b3 = (const float*)d_in[7];
    float2* out = (float2*)d_out;

    const int* src = ei;
    const int* dst = ei + NED;

    char* p = (char*)d_ws;
    float* dinv   = (float*)p; p += align256(sizeof(float) * (size_t)NND);
    int*   rowptr = (int*)p;   p += align256(sizeof(int) * (size_t)(NND + 1));
    int*   excl   = (int*)p;   p += align256(sizeof(int) * (size_t)(SCAN_N + 1));
    int*   bsums  = (int*)p;   p += align256(sizeof(int) * 128);
    int*   ssrc   = (int*)p;   p += align256(sizeof(int) * (size_t)NED);
    half4n* t4    = (half4n*)p; p += align256(sizeof(half4n) * (size_t)NND);
    float2* t3    = (float2*)p; p += align256(sizeof(float2) * (size_t)NND);
    // region shared by tmp (dead after k_bucket) and t16 (written after)
    char*  q      = p;         p += align256(sizeof(int) * (size_t)NED);
    int*   tmp    = (int*)q;
    _Float16* t16 = (_Float16*)q;                                // [NND][16] fp16

    const int B = 256;
    const int gridN = (NND + B - 1) / B;
    const int grid2N = (NND * 2 + B - 1) / B;

    // ---- CSR build (scan2/scan3 folded into consumers) ----
    k_hist<<<NCHUNK, B, 0, stream>>>(dst, excl);
    k_scan1<<<NSB, 256, 0, stream>>>(excl, excl, bsums, SCAN_N);
    k_part<<<NCHUNK, B, 0, stream>>>(src, dst, excl, bsums, tmp);
    k_bucket<<<NB, B, 0, stream>>>(excl, bsums, tmp, ssrc, rowptr, dinv, x, t4);

    // ---- layer 1: aggregate fp16 4-wide, fused 3->16, fp16 table out ----
    k_g4mm1<<<gridN, B, 0, stream>>>(rowptr, ssrc, t4, dinv, W1, b1, t16, NND);

    // ---- layer 2: 16-wide fp16 gather (2 lanes/node) + fused W2/relu/W3 -> t3 ----
    k_g16mm<<<grid2N, B, 0, stream>>>(rowptr, ssrc, t16, dinv, W2, b2, W3, t3, NND);

    // ---- layer 3: gather 2-wide ----
    k_g2<<<gridN, B, 0, stream>>>(rowptr, ssrc, t3, dinv, b3, out, NND);
}